// Round 4
// baseline (569.179 us; speedup 1.0000x reference)
//
#include <hip/hip_runtime.h>
#include <math.h>

// Problem constants: x [16,64,256,256] f32, mask [16,256,256] i32
#define BATCH 16
#define CH    64
#define HW4   16384          // 256*256/4 (float4 units)
#define NBLK  2048           // 128 blocks/batch * 16 batches (128-thr blocks)

#define RED4(t)                                                   \
    vmax.x = fmaxf(vmax.x, (t).x); vmax.y = fmaxf(vmax.y, (t).y); \
    vmax.z = fmaxf(vmax.z, (t).z); vmax.w = fmaxf(vmax.w, (t).w); \
    vmin.x = fminf(vmin.x, (t).x); vmin.y = fminf(vmin.y, (t).y); \
    vmin.z = fminf(vmin.z, (t).z); vmin.w = fminf(vmin.w, (t).w); \
    vsum.x += (t).x; vsum.y += (t).y; vsum.z += (t).z; vsum.w += (t).w;

#define NORMW(dst, src, m, r)                                  \
    (dst).x = (mk.x == 1) ? ((src).x - (m)) * (r) : 0.0f;      \
    (dst).y = (mk.y == 1) ? ((src).y - (m)) * (r) : 0.0f;      \
    (dst).z = (mk.z == 1) ? ((src).z - (m)) * (r) : 0.0f;      \
    (dst).w = (mk.w == 1) ? ((src).w - (m)) * (r) : 0.0f;

// Fused pool+stats+normalize WITHOUT cooperative launch (R1's coop path
// collapsed codegen to VGPR=32 / serial loads). Pool body is byte-identical
// to the verified R2 kernel; convergence is hand-rolled:
//   - threads 0..6 (lanes of wave 0) atomicAdd 7 partials into acc[b]
//   - lane 0 release-fetch_adds an arrival counter (same wave => ordered
//     after the partial adds), then spin-waits acquire until all 128
//     blocks of batch b arrived
//   - stats read back via agent-scope atomic loads (coherent across the
//     non-coherent per-XCD L2s), normalize register-held max/mean/min,
//     write out ONCE.
// Residency: 2048 blocks x 128 thr, VGPR<=128 => exactly 8 blocks/CU of a
// 16-block capacity -> whole grid co-resident, spin cannot deadlock.
// ws layout: acc = float[16][8] (cnt,S1[3],S2[3],pad), cnt = int[16] after.
__global__ __launch_bounds__(128, 4) void fused_pool_norm(
    const float* __restrict__ x, const int* __restrict__ mask,
    float* __restrict__ out, float* __restrict__ ws)
{
    float* acc = ws;                       // [16][8]
    int*   cnt = (int*)(ws + BATCH * 8);   // [16]

    const int b    = blockIdx.x >> 7;           // batch
    const int pblk = blockIdx.x & 127;          // pixel-block within batch
    const int idx4 = pblk * 128 + threadIdx.x;  // float4 index in [0, HW4)

    const float4* xb = (const float4*)x + (size_t)b * CH * HW4 + idx4;

    // mask load first; latency hides under the x stream
    const int4 mk = ((const int4*)mask)[(size_t)b * HW4 + idx4];

    float4 vmax = make_float4(-INFINITY, -INFINITY, -INFINITY, -INFINITY);
    float4 vmin = make_float4( INFINITY,  INFINITY,  INFINITY,  INFINITY);
    float4 vsum = make_float4(0.f, 0.f, 0.f, 0.f);

    // 8 channels in flight: t[8] = 32 VGPRs of load data (verified R2 body)
    for (int c0 = 0; c0 < CH; c0 += 8) {
        float4 t[8];
#pragma unroll
        for (int j = 0; j < 8; ++j)
            t[j] = xb[(size_t)(c0 + j) * HW4];
#pragma unroll
        for (int j = 0; j < 8; ++j) { RED4(t[j]); }
    }

    const float inv = 1.0f / 64.0f;
    float4 vmean = make_float4(vsum.x * inv, vsum.y * inv, vsum.z * inv, vsum.w * inv);

    // masked partial sums for this thread's 4 pixels
    float vals[7] = {0.f, 0.f, 0.f, 0.f, 0.f, 0.f, 0.f}; // cnt, S1[3], S2[3]
    if (mk.x == 1) { vals[0] += 1.f;
        vals[1] += vmax.x;  vals[4] += vmax.x  * vmax.x;
        vals[2] += vmean.x; vals[5] += vmean.x * vmean.x;
        vals[3] += vmin.x;  vals[6] += vmin.x  * vmin.x; }
    if (mk.y == 1) { vals[0] += 1.f;
        vals[1] += vmax.y;  vals[4] += vmax.y  * vmax.y;
        vals[2] += vmean.y; vals[5] += vmean.y * vmean.y;
        vals[3] += vmin.y;  vals[6] += vmin.y  * vmin.y; }
    if (mk.z == 1) { vals[0] += 1.f;
        vals[1] += vmax.z;  vals[4] += vmax.z  * vmax.z;
        vals[2] += vmean.z; vals[5] += vmean.z * vmean.z;
        vals[3] += vmin.z;  vals[6] += vmin.z  * vmin.z; }
    if (mk.w == 1) { vals[0] += 1.f;
        vals[1] += vmax.w;  vals[4] += vmax.w  * vmax.w;
        vals[2] += vmean.w; vals[5] += vmean.w * vmean.w;
        vals[3] += vmin.w;  vals[6] += vmin.w  * vmin.w; }

    // wave (64-lane) shuffle reduction
    for (int off = 32; off > 0; off >>= 1) {
#pragma unroll
        for (int k = 0; k < 7; ++k)
            vals[k] += __shfl_down(vals[k], off, 64);
    }

    // cross-wave (2 waves) LDS combine
    __shared__ float red[2][8];
    const int lane = threadIdx.x & 63;
    const int wid  = threadIdx.x >> 6;
    if (lane == 0) {
#pragma unroll
        for (int k = 0; k < 7; ++k) red[wid][k] = vals[k];
    }
    __syncthreads();

    // device-scope accumulate (lanes 0..6 of wave 0) + release arrival
    if (threadIdx.x < 7) {
        const int k = threadIdx.x;
        __hip_atomic_fetch_add(&acc[b * 8 + k], red[0][k] + red[1][k],
                               __ATOMIC_RELAXED, __HIP_MEMORY_SCOPE_AGENT);
    }
    if (threadIdx.x == 0) {
        // same wave as the adds above -> release orders them before arrival
        __hip_atomic_fetch_add(&cnt[b], 1,
                               __ATOMIC_RELEASE, __HIP_MEMORY_SCOPE_AGENT);
        while (__hip_atomic_load(&cnt[b], __ATOMIC_ACQUIRE,
                                 __HIP_MEMORY_SCOPE_AGENT) < 128)
            __builtin_amdgcn_s_sleep(2);
    }
    __syncthreads();   // rest of block parks here while lane 0 spins

    // finalize stats (uniform-address agent atomic loads: 7 per thread)
    float s[7];
#pragma unroll
    for (int k = 0; k < 7; ++k)
        s[k] = __hip_atomic_load(&acc[b * 8 + k],
                                 __ATOMIC_RELAXED, __HIP_MEMORY_SCOPE_AGENT);
    const float n     = s[0];
    const float mean0 = s[1] / n, mean1 = s[2] / n, mean2 = s[3] / n;
    const float rstd0 = 1.0f / sqrtf((s[4] - s[1] * s[1] / n) / (n - 1.0f));
    const float rstd1 = 1.0f / sqrtf((s[5] - s[2] * s[2] / n) / (n - 1.0f));
    const float rstd2 = 1.0f / sqrtf((s[6] - s[3] * s[3] / n) / (n - 1.0f));

    // normalize register-held pooled values; write out ONCE
    float4* ob = (float4*)out + (size_t)b * 3 * HW4 + idx4;
    float4 o;
    NORMW(o, vmax,  mean0, rstd0);  ob[0]       = o;   // c=0: max
    NORMW(o, vmean, mean1, rstd1);  ob[HW4]     = o;   // c=1: mean
    NORMW(o, vmin,  mean2, rstd2);  ob[2 * HW4] = o;   // c=2: min
}

extern "C" void kernel_launch(void* const* d_in, const int* in_sizes, int n_in,
                              void* d_out, int out_size, void* d_ws, size_t ws_size,
                              hipStream_t stream)
{
    const float* x    = (const float*)d_in[0];
    const int*   mask = (const int*)d_in[1];
    float*       out  = (float*)d_out;
    float*       ws   = (float*)d_ws;

    // acc[16][8] + cnt[16] live in poisoned workspace -> zero them (1 KB).
    hipMemsetAsync(ws, 0, 1024, stream);
    fused_pool_norm<<<NBLK, 128, 0, stream>>>(x, mask, out, ws);
}

// Round 6
// 353.378 us; speedup vs baseline: 1.6107x; 1.6107x over previous
//
#include <hip/hip_runtime.h>
#include <math.h>

// Problem constants: x [16,64,256,256] f32, mask [16,256,256] i32
#define BATCH 16
#define CH    64
#define HW    65536          // 256*256
#define HW4   16384          // HW/4 (float4 units)
#define NBLKA 2048           // pool: 128 blocks/batch * 16 batches (128-thr blocks)

// native Clang vector type: __builtin_nontemporal_load requires it
typedef float vf4 __attribute__((ext_vector_type(4)));

#define RED4(t)                                                   \
    vmax.x = fmaxf(vmax.x, (t).x); vmax.y = fmaxf(vmax.y, (t).y); \
    vmax.z = fmaxf(vmax.z, (t).z); vmax.w = fmaxf(vmax.w, (t).w); \
    vmin.x = fminf(vmin.x, (t).x); vmin.y = fminf(vmin.y, (t).y); \
    vmin.z = fminf(vmin.z, (t).z); vmin.w = fminf(vmin.w, (t).w); \
    vsum.x += (t).x; vsum.y += (t).y; vsum.z += (t).z; vsum.w += (t).w;

// ws: per-block partials, 8 floats each: cnt, S1[3], S2[3], pad.
// Contention-free slots -> no init needed (every slot written before read).

// R2 body verified at 371.2 total (pool+norm ~= 120 us after the ~251 us
// harness floor). Single change: NON-TEMPORAL loads on the x stream. x has
// zero reuse (each byte read exactly once), so L1 allocation is pure
// overhead; theory: pool's 2.8 TB/s == per-CU L1 miss-queue ceiling
// (~32 x 128B lines / 900cy ~= 10.9 GB/s/CU ~= 2.8 TB/s chip-wide).
// nt loads bypass L1 -> deeper memory queueing. Mask loads stay cached
// (norm re-reads mask; L2 reuse wanted).
__global__ __launch_bounds__(128, 4) void pool_stats_kernel(
    const float* __restrict__ x, const int* __restrict__ mask,
    float* __restrict__ out, float* __restrict__ part)
{
    const int b    = blockIdx.x >> 7;           // batch
    const int pblk = blockIdx.x & 127;          // pixel-block within batch
    const int idx4 = pblk * 128 + threadIdx.x;  // float4 index in [0, HW4)

    const vf4* xb = (const vf4*)x + (size_t)b * CH * HW4 + idx4;

    // issue the mask load first; its latency hides under the x reads
    const int4 mk = ((const int4*)mask)[(size_t)b * HW4 + idx4];

    float4 vmax = make_float4(-INFINITY, -INFINITY, -INFINITY, -INFINITY);
    float4 vmin = make_float4( INFINITY,  INFINITY,  INFINITY,  INFINITY);
    float4 vsum = make_float4(0.f, 0.f, 0.f, 0.f);

    // 8 channels in flight: t[8] = 32 VGPRs of load data, ~60 VGPRs total.
    for (int c0 = 0; c0 < CH; c0 += 8) {
        vf4 t[8];
#pragma unroll
        for (int j = 0; j < 8; ++j)
            t[j] = __builtin_nontemporal_load(xb + (size_t)(c0 + j) * HW4);
#pragma unroll
        for (int j = 0; j < 8; ++j) { RED4(t[j]); }
    }

    const float inv = 1.0f / 64.0f;
    float4 vmean = make_float4(vsum.x * inv, vsum.y * inv, vsum.z * inv, vsum.w * inv);

    // write pooled channels [max, mean, min] into d_out [B,3,H,W]
    float4* ob = (float4*)out + (size_t)b * 3 * HW4 + idx4;
    ob[0]       = vmax;
    ob[HW4]     = vmean;
    ob[2 * HW4] = vmin;

    // masked partial sums for this thread's 4 pixels
    float vals[7] = {0.f, 0.f, 0.f, 0.f, 0.f, 0.f, 0.f}; // cnt, S1[3], S2[3]
    if (mk.x == 1) { vals[0] += 1.f;
        vals[1] += vmax.x;  vals[4] += vmax.x  * vmax.x;
        vals[2] += vmean.x; vals[5] += vmean.x * vmean.x;
        vals[3] += vmin.x;  vals[6] += vmin.x  * vmin.x; }
    if (mk.y == 1) { vals[0] += 1.f;
        vals[1] += vmax.y;  vals[4] += vmax.y  * vmax.y;
        vals[2] += vmean.y; vals[5] += vmean.y * vmean.y;
        vals[3] += vmin.y;  vals[6] += vmin.y  * vmin.y; }
    if (mk.z == 1) { vals[0] += 1.f;
        vals[1] += vmax.z;  vals[4] += vmax.z  * vmax.z;
        vals[2] += vmean.z; vals[5] += vmean.z * vmean.z;
        vals[3] += vmin.z;  vals[6] += vmin.z  * vmin.z; }
    if (mk.w == 1) { vals[0] += 1.f;
        vals[1] += vmax.w;  vals[4] += vmax.w  * vmax.w;
        vals[2] += vmean.w; vals[5] += vmean.w * vmean.w;
        vals[3] += vmin.w;  vals[6] += vmin.w  * vmin.w; }

    // wave (64-lane) shuffle reduction
    for (int off = 32; off > 0; off >>= 1) {
#pragma unroll
        for (int k = 0; k < 7; ++k)
            vals[k] += __shfl_down(vals[k], off, 64);
    }

    // cross-wave (2 waves) LDS reduction -> one contention-free slot per block
    __shared__ float red[2][8];
    const int lane = threadIdx.x & 63;
    const int wid  = threadIdx.x >> 6;
    if (lane == 0) {
#pragma unroll
        for (int k = 0; k < 7; ++k) red[wid][k] = vals[k];
    }
    __syncthreads();
    if (threadIdx.x < 7) {
        const int k = threadIdx.x;
        part[blockIdx.x * 8 + k] = red[0][k] + red[1][k];
    }
}

// One block per 256 float4s of out; folds stats finalization (redundant
// per-block reduce of 128 partial slots, ~4 KB from L2) + masked normalize.
__global__ __launch_bounds__(256) void norm_kernel(
    float* __restrict__ out, const int* __restrict__ mask,
    const float* __restrict__ part)
{
    const int i4   = blockIdx.x * 256 + threadIdx.x;   // [0, 3*B*HW4)
    const int bc   = i4 >> 14;                         // (b*3 + c)
    const int idx4 = i4 & (HW4 - 1);
    const int b    = bc / 3;

    // redundant stats reduce: batch b's 128 partial slots (2 per lane)
    __shared__ float sstat[6];   // mean[3], rstd[3]
    if (threadIdx.x < 64) {
        const float* pb = part + (size_t)(b * 128 + threadIdx.x * 2) * 8;
        float s[7];
#pragma unroll
        for (int k = 0; k < 7; ++k) s[k] = pb[k] + pb[8 + k];
        for (int off = 32; off > 0; off >>= 1) {
#pragma unroll
            for (int k = 0; k < 7; ++k)
                s[k] += __shfl_down(s[k], off, 64);
        }
        if (threadIdx.x == 0) {
            const float cnt = s[0];
#pragma unroll
            for (int c = 0; c < 3; ++c) {
                const float S1 = s[1 + c];
                const float S2 = s[4 + c];
                sstat[c]     = S1 / cnt;
                sstat[3 + c] = 1.0f / sqrtf((S2 - S1 * S1 / cnt) / (cnt - 1.0f));
            }
        }
    }
    __syncthreads();

    const int   c    = bc - b * 3;
    const float mean = sstat[c];
    const float rstd = sstat[3 + c];

    float4 v = ((const float4*)out)[i4];
    int4 mk  = ((const int4*)mask)[(size_t)b * HW4 + idx4];
    v.x = (mk.x == 1) ? (v.x - mean) * rstd : 0.0f;
    v.y = (mk.y == 1) ? (v.y - mean) * rstd : 0.0f;
    v.z = (mk.z == 1) ? (v.z - mean) * rstd : 0.0f;
    v.w = (mk.w == 1) ? (v.w - mean) * rstd : 0.0f;
    ((float4*)out)[i4] = v;
}

extern "C" void kernel_launch(void* const* d_in, const int* in_sizes, int n_in,
                              void* d_out, int out_size, void* d_ws, size_t ws_size,
                              hipStream_t stream)
{
    const float* x    = (const float*)d_in[0];
    const int*   mask = (const int*)d_in[1];
    float*       out  = (float*)d_out;
    float*       part = (float*)d_ws;

    pool_stats_kernel<<<NBLKA, 128, 0, stream>>>(x, mask, out, part);
    norm_kernel<<<3 * BATCH * HW4 / 256, 256, 0, stream>>>(out, mask, part);
}

// Round 7
// 350.270 us; speedup vs baseline: 1.6250x; 1.0089x over previous
//
#include <hip/hip_runtime.h>
#include <math.h>

// Problem constants: x [16,64,256,256] f32, mask [16,256,256] i32
#define BATCH 16
#define CH    64
#define HW    65536          // 256*256
#define HW4   16384          // HW/4 (float4 units)
#define NBLKP 512            // pool: 32 blocks/batch * 16 batches (256-thr, P=2)

// native Clang vector type: __builtin_nontemporal_load requires it
typedef float vf4 __attribute__((ext_vector_type(4)));

#define RED4(acc_max, acc_min, acc_sum, t)                                            \
    (acc_max).x = fmaxf((acc_max).x, (t).x); (acc_max).y = fmaxf((acc_max).y, (t).y); \
    (acc_max).z = fmaxf((acc_max).z, (t).z); (acc_max).w = fmaxf((acc_max).w, (t).w); \
    (acc_min).x = fminf((acc_min).x, (t).x); (acc_min).y = fminf((acc_min).y, (t).y); \
    (acc_min).z = fminf((acc_min).z, (t).z); (acc_min).w = fminf((acc_min).w, (t).w); \
    (acc_sum).x += (t).x; (acc_sum).y += (t).y; (acc_sum).z += (t).z; (acc_sum).w += (t).w;

#define STAT1(mkc, mx, mn, me)                       \
    if ((mkc) == 1) { vals[0] += 1.f;                \
        vals[1] += (mx); vals[4] += (mx) * (mx);     \
        vals[2] += (me); vals[5] += (me) * (me);     \
        vals[3] += (mn); vals[6] += (mn) * (mn); }

// Granularity experiment (nt loads kept from R6's verified win):
// 256-thr blocks, P=2 adjacent pixels/thread -> per plane visit the block
// reads float4 range [pblk*512, pblk*512+512) = 8 KB CONTIGUOUS (vs 1 KB
// islands in R6). 8 channels deep x 2 pixels = 16 loads in flight/wave
// (16 KB/wave x 8 waves/CU = 128 KB/CU outstanding — same as R6, so the
// queue-starvation confound from R3 is removed). Theory: the remaining
// 3.0-vs-6.3 TB/s wall is DRAM/fabric efficiency at 1 KB gather granules.
__global__ __launch_bounds__(256, 4) void pool_stats_kernel(
    const float* __restrict__ x, const int* __restrict__ mask,
    float* __restrict__ out, float* __restrict__ part)
{
    const int b    = blockIdx.x >> 5;            // batch (32 blocks/batch)
    const int pblk = blockIdx.x & 31;            // pixel-block within batch
    const int i0   = pblk * 512 + threadIdx.x;   // 1st float4; 2nd = i0+256

    const vf4* xb = (const vf4*)x + (size_t)b * CH * HW4 + i0;

    // mask loads first; latency hides under the x stream
    const int4 mk0 = ((const int4*)mask)[(size_t)b * HW4 + i0];
    const int4 mk1 = ((const int4*)mask)[(size_t)b * HW4 + i0 + 256];

    float4 max0 = make_float4(-INFINITY, -INFINITY, -INFINITY, -INFINITY);
    float4 max1 = max0;
    float4 min0 = make_float4( INFINITY,  INFINITY,  INFINITY,  INFINITY);
    float4 min1 = min0;
    float4 sum0 = make_float4(0.f, 0.f, 0.f, 0.f);
    float4 sum1 = sum0;

    // 8 channels x 2 pixels = 16 nt loads in flight (64 VGPRs of data).
    for (int c0 = 0; c0 < CH; c0 += 8) {
        vf4 t[8][2];
#pragma unroll
        for (int j = 0; j < 8; ++j) {
            const vf4* p = xb + (size_t)(c0 + j) * HW4;
            t[j][0] = __builtin_nontemporal_load(p);
            t[j][1] = __builtin_nontemporal_load(p + 256);
        }
#pragma unroll
        for (int j = 0; j < 8; ++j) {
            RED4(max0, min0, sum0, t[j][0]);
            RED4(max1, min1, sum1, t[j][1]);
        }
    }

    const float inv = 1.0f / 64.0f;
    float4 mean0 = make_float4(sum0.x * inv, sum0.y * inv, sum0.z * inv, sum0.w * inv);
    float4 mean1 = make_float4(sum1.x * inv, sum1.y * inv, sum1.z * inv, sum1.w * inv);

    // write pooled channels [max, mean, min] into d_out [B,3,H,W]
    float4* ob = (float4*)out + (size_t)b * 3 * HW4 + i0;
    ob[0]           = max0;  ob[256]           = max1;
    ob[HW4]         = mean0; ob[HW4 + 256]     = mean1;
    ob[2 * HW4]     = min0;  ob[2 * HW4 + 256] = min1;

    // masked partial sums for this thread's 8 pixels
    float vals[7] = {0.f, 0.f, 0.f, 0.f, 0.f, 0.f, 0.f}; // cnt, S1[3], S2[3]
    STAT1(mk0.x, max0.x, min0.x, mean0.x)
    STAT1(mk0.y, max0.y, min0.y, mean0.y)
    STAT1(mk0.z, max0.z, min0.z, mean0.z)
    STAT1(mk0.w, max0.w, min0.w, mean0.w)
    STAT1(mk1.x, max1.x, min1.x, mean1.x)
    STAT1(mk1.y, max1.y, min1.y, mean1.y)
    STAT1(mk1.z, max1.z, min1.z, mean1.z)
    STAT1(mk1.w, max1.w, min1.w, mean1.w)

    // wave (64-lane) shuffle reduction
    for (int off = 32; off > 0; off >>= 1) {
#pragma unroll
        for (int k = 0; k < 7; ++k)
            vals[k] += __shfl_down(vals[k], off, 64);
    }

    // cross-wave (4 waves) LDS reduction -> one contention-free slot per block
    __shared__ float red[4][8];
    const int lane = threadIdx.x & 63;
    const int wid  = threadIdx.x >> 6;
    if (lane == 0) {
#pragma unroll
        for (int k = 0; k < 7; ++k) red[wid][k] = vals[k];
    }
    __syncthreads();
    if (threadIdx.x < 7) {
        const int k = threadIdx.x;
        part[blockIdx.x * 8 + k] = red[0][k] + red[1][k] + red[2][k] + red[3][k];
    }
}

// One block per 256 float4s of out; folds stats finalization (redundant
// per-block reduce of batch b's 32 partial slots, ~1 KB from L2) + normalize.
__global__ __launch_bounds__(256) void norm_kernel(
    float* __restrict__ out, const int* __restrict__ mask,
    const float* __restrict__ part)
{
    const int i4   = blockIdx.x * 256 + threadIdx.x;   // [0, 3*B*HW4)
    const int bc   = i4 >> 14;                         // (b*3 + c)
    const int idx4 = i4 & (HW4 - 1);
    const int b    = bc / 3;

    // redundant stats reduce: batch b's 32 partial slots (lanes 0..31)
    __shared__ float sstat[6];   // mean[3], rstd[3]
    if (threadIdx.x < 64) {
        const float* pb = part + (size_t)(b * 32 + (threadIdx.x & 31)) * 8;
        const float w   = (threadIdx.x < 32) ? 1.0f : 0.0f;
        float s[7];
#pragma unroll
        for (int k = 0; k < 7; ++k) s[k] = w * pb[k];
        for (int off = 32; off > 0; off >>= 1) {
#pragma unroll
            for (int k = 0; k < 7; ++k)
                s[k] += __shfl_down(s[k], off, 64);
        }
        if (threadIdx.x == 0) {
            const float cnt = s[0];
#pragma unroll
            for (int c = 0; c < 3; ++c) {
                const float S1 = s[1 + c];
                const float S2 = s[4 + c];
                sstat[c]     = S1 / cnt;
                sstat[3 + c] = 1.0f / sqrtf((S2 - S1 * S1 / cnt) / (cnt - 1.0f));
            }
        }
    }
    __syncthreads();

    const int   c    = bc - b * 3;
    const float mean = sstat[c];
    const float rstd = sstat[3 + c];

    float4 v = ((const float4*)out)[i4];
    int4 mk  = ((const int4*)mask)[(size_t)b * HW4 + idx4];
    v.x = (mk.x == 1) ? (v.x - mean) * rstd : 0.0f;
    v.y = (mk.y == 1) ? (v.y - mean) * rstd : 0.0f;
    v.z = (mk.z == 1) ? (v.z - mean) * rstd : 0.0f;
    v.w = (mk.w == 1) ? (v.w - mean) * rstd : 0.0f;
    ((float4*)out)[i4] = v;
}

extern "C" void kernel_launch(void* const* d_in, const int* in_sizes, int n_in,
                              void* d_out, int out_size, void* d_ws, size_t ws_size,
                              hipStream_t stream)
{
    const float* x    = (const float*)d_in[0];
    const int*   mask = (const int*)d_in[1];
    float*       out  = (float*)d_out;
    float*       part = (float*)d_ws;   // 512 * 8 floats = 16 KB

    pool_stats_kernel<<<NBLKP, 256, 0, stream>>>(x, mask, out, part);
    norm_kernel<<<3 * BATCH * HW4 / 256, 256, 0, stream>>>(out, mask, part);
}